// Round 3
// baseline (1622.292 us; speedup 1.0000x reference)
//
#include <hip/hip_runtime.h>

#define N_NODES 100000
#define N_EDGES 3200000
#define N_GRAPHS 2048
#define H 64
#define N_LAYERS 3

#define SCAN_ELEMS 1024
#define NB_SCAN ((N_NODES + SCAN_ELEMS - 1) / SCAN_ELEMS)  // 98

#define BUCK_BITS 7
#define BUCK_NODES (1 << BUCK_BITS)                          // 128 nodes / bucket
#define NBUCK ((N_NODES + BUCK_NODES - 1) / BUCK_NODES)      // 782

// ---------------- kernels ----------------

// zero degree histogram, bucket cursors, pooled sums, counts
__global__ void k_init(int* degi, int* bcur, float* sums, float* cnt) {
    int i = blockIdx.x * blockDim.x + threadIdx.x;
    if (i < N_NODES) degi[i] = 0;
    if (i < NBUCK) bcur[i] = 0;
    if (i < N_GRAPHS * H) sums[i] = 0.0f;
    if (i < N_GRAPHS) cnt[i] = 0.0f;
}

// degree histogram over target (col) indices
__global__ void k_hist(const int* __restrict__ col, int* __restrict__ degi) {
    int e = blockIdx.x * blockDim.x + threadIdx.x;
    if (e < N_EDGES) atomicAdd(&degi[col[e]], 1);
}

// exclusive scan, stage 1: each block scans 1024 elements (4/thread)
__global__ void k_scan1(const int* __restrict__ in, int* __restrict__ out,
                        int* __restrict__ bsums) {
    __shared__ int s[256];
    int b = blockIdx.x, tid = threadIdx.x;
    int base = b * SCAN_ELEMS + tid * 4;
    int v0 = (base + 0 < N_NODES) ? in[base + 0] : 0;
    int v1 = (base + 1 < N_NODES) ? in[base + 1] : 0;
    int v2 = (base + 2 < N_NODES) ? in[base + 2] : 0;
    int v3 = (base + 3 < N_NODES) ? in[base + 3] : 0;
    int tsum = v0 + v1 + v2 + v3;
    s[tid] = tsum;
    __syncthreads();
    for (int off = 1; off < 256; off <<= 1) {
        int x = (tid >= off) ? s[tid - off] : 0;
        __syncthreads();
        s[tid] += x;
        __syncthreads();
    }
    int excl = s[tid] - tsum;
    if (base + 0 < N_NODES) out[base + 0] = excl;
    if (base + 1 < N_NODES) out[base + 1] = excl + v0;
    if (base + 2 < N_NODES) out[base + 2] = excl + v0 + v1;
    if (base + 3 < N_NODES) out[base + 3] = excl + v0 + v1 + v2;
    if (tid == 0) bsums[b] = s[255];
}

// stage 2: scan the 98 block sums (single block, 128 threads)
__global__ void k_scan2(int* __restrict__ bsums, int* __restrict__ boffs) {
    __shared__ int s[128];
    int tid = threadIdx.x;
    int v = (tid < NB_SCAN) ? bsums[tid] : 0;
    s[tid] = v;
    __syncthreads();
    for (int off = 1; off < 128; off <<= 1) {
        int x = (tid >= off) ? s[tid - off] : 0;
        __syncthreads();
        s[tid] += x;
        __syncthreads();
    }
    if (tid < NB_SCAN) boffs[tid] = s[tid] - v;  // exclusive
}

// stage 3: add block offsets -> row_start; init cursor; dinv = rsqrt(deg+1)
__global__ void k_scan3(const int* __restrict__ scanned, const int* __restrict__ boffs,
                        const int* __restrict__ degi, int* __restrict__ row_start,
                        int* __restrict__ cursor, float* __restrict__ dinv) {
    int i = blockIdx.x * blockDim.x + threadIdx.x;
    if (i >= N_NODES) return;
    int rs = scanned[i] + boffs[i / SCAN_ELEMS];
    row_start[i] = rs;
    cursor[i] = rs;
    dinv[i] = rsqrtf((float)(degi[i] + 1));  // +1 self-loop
}

// pass A: bin (row,col) pairs into per-bucket staging regions.
// bucket cursor advances sequentially -> full-line fills, no write amplification.
__global__ void k_binA(const int* __restrict__ row, const int* __restrict__ col,
                       const int* __restrict__ row_start, int* __restrict__ bcur,
                       int2* __restrict__ staging) {
    int e = blockIdx.x * blockDim.x + threadIdx.x;
    if (e >= N_EDGES) return;
    int c = col[e];
    int b = c >> BUCK_BITS;
    int base = row_start[b << BUCK_BITS];  // bucket base in edge space
    int pos = atomicAdd(&bcur[b], 1);
    staging[base + pos] = make_int2(row[e], c);
}

// pass B: one block per bucket; finish the sort within a ~16KB L2-resident window
__global__ void k_binB(const int2* __restrict__ staging, const int* __restrict__ row_start,
                       int* __restrict__ cursor, int* __restrict__ sorted_row) {
    int b = blockIdx.x;
    int n0 = b << BUCK_BITS;
    int n1 = n0 + BUCK_NODES;
    int base = row_start[n0];
    int end = (n1 >= N_NODES) ? N_EDGES : row_start[n1];
    for (int i = base + threadIdx.x; i < end; i += blockDim.x) {
        int2 p = staging[i];
        int pos = atomicAdd(&cursor[p.y], 1);
        sorted_row[pos] = p.x;
    }
}

// h = emb[x]
__global__ void k_embed(const int* __restrict__ x, const float* __restrict__ emb,
                        float* __restrict__ h) {
    int i = blockIdx.x * blockDim.x + threadIdx.x;
    if (i >= N_NODES * H) return;
    int n = i >> 6, c = i & 63;
    h[i] = emb[x[n] * H + c];
}

// t' = dinv[n] * (h @ W)   (block = 4 nodes x 64 channels)
__global__ void k_linear(const float* __restrict__ h, const float* __restrict__ W,
                         const float* __restrict__ dinv, float* __restrict__ t) {
    __shared__ float sW[H * H];
    __shared__ float sh[4][H];
    int tid = threadIdx.x;
    for (int i = tid; i < H * H; i += 256) sW[i] = W[i];
    int r = tid >> 6, c = tid & 63;
    int n = blockIdx.x * 4 + r;
    sh[r][c] = (n < N_NODES) ? h[n * H + c] : 0.0f;
    __syncthreads();
    if (n < N_NODES) {
        float acc = 0.0f;
#pragma unroll
        for (int k = 0; k < H; ++k) acc += sh[r][k] * sW[k * H + c];
        t[n * H + c] = acc * dinv[n];
    }
}

// fused gather + finalize: one wave per node, lane = channel
__global__ void k_gather(const int* __restrict__ sorted_row, const int* __restrict__ row_start,
                         const int* __restrict__ degi, const float* __restrict__ t,
                         const float* __restrict__ dinv, const float* __restrict__ b,
                         float* __restrict__ h, int layer) {
    int gid = blockIdx.x * blockDim.x + threadIdx.x;
    int n = gid >> 6;
    int lane = gid & 63;
    if (n >= N_NODES) return;
    int start = row_start[n];
    int d = degi[n];
    float acc = t[n * H + lane];  // self-loop term
    int e = 0;
    for (; e + 4 <= d; e += 4) {
        int r0 = sorted_row[start + e + 0];
        int r1 = sorted_row[start + e + 1];
        int r2 = sorted_row[start + e + 2];
        int r3 = sorted_row[start + e + 3];
        float a0 = t[r0 * H + lane];
        float a1 = t[r1 * H + lane];
        float a2 = t[r2 * H + lane];
        float a3 = t[r3 * H + lane];
        acc += a0 + a1 + a2 + a3;
    }
    for (; e < d; ++e) acc += t[sorted_row[start + e] * H + lane];
    float v = fmaxf(acc * dinv[n] + b[lane], 0.0f);
    h[n * H + lane] = (layer == 0) ? v : h[n * H + lane] + v;
}

// segmented mean-pool: each wave owns 128 consecutive nodes (batch is sorted),
// accumulates in registers, flushes at graph boundaries.
__global__ void k_pool2(const float* __restrict__ h, const int* __restrict__ batch,
                        float* __restrict__ sums, float* __restrict__ cnt) {
    const int CH = 128;
    int wave = (blockIdx.x * blockDim.x + threadIdx.x) >> 6;
    int lane = threadIdx.x & 63;
    int n0 = wave * CH;
    if (n0 >= N_NODES) return;
    int n1 = n0 + CH;
    if (n1 > N_NODES) n1 = N_NODES;
    int g_cur = batch[n0];
    float acc = 0.0f;
    int c = 0;
    for (int n = n0; n < n1; ++n) {
        int g = batch[n];
        if (g != g_cur) {
            atomicAdd(&sums[g_cur * H + lane], acc);
            if (lane == 0) atomicAdd(&cnt[g_cur], (float)c);
            acc = 0.0f; c = 0; g_cur = g;
        }
        acc += h[n * H + lane];
        ++c;
    }
    atomicAdd(&sums[g_cur * H + lane], acc);
    if (lane == 0) atomicAdd(&cnt[g_cur], (float)c);
}

// predictor MLP: one block (64 threads) per graph
__global__ void k_mlp(const float* __restrict__ sums, const float* __restrict__ cnt,
                      const float* __restrict__ w1, const float* __restrict__ b1,
                      const float* __restrict__ w2, const float* __restrict__ b2,
                      const float* __restrict__ w3, const float* __restrict__ b3,
                      float* __restrict__ out) {
    __shared__ float sg[H];
    __shared__ float s1[32];
    __shared__ float s2[16];
    int g = blockIdx.x, tid = threadIdx.x;
    float inv = 1.0f / fmaxf(cnt[g], 1.0f);
    sg[tid] = sums[g * H + tid] * inv;
    __syncthreads();
    if (tid < 32) {
        float acc = b1[tid];
#pragma unroll
        for (int k = 0; k < H; ++k) acc += sg[k] * w1[k * 32 + tid];
        s1[tid] = fmaxf(acc, 0.0f);
    }
    __syncthreads();
    if (tid < 16) {
        float acc = b2[tid];
#pragma unroll
        for (int k = 0; k < 32; ++k) acc += s1[k] * w2[k * 16 + tid];
        s2[tid] = fmaxf(acc, 0.0f);
    }
    __syncthreads();
    if (tid == 0) {
        float acc = b3[0];
#pragma unroll
        for (int k = 0; k < 16; ++k) acc += s2[k] * w3[k];
        out[g] = acc;
    }
}

// ---------------- launch ----------------

extern "C" void kernel_launch(void* const* d_in, const int* in_sizes, int n_in,
                              void* d_out, int out_size, void* d_ws, size_t ws_size,
                              hipStream_t stream) {
    const int*   x      = (const int*)d_in[0];
    const int*   eidx   = (const int*)d_in[1];   // (2, E): row = eidx, col = eidx + E
    const int*   batch  = (const int*)d_in[2];
    const float* emb    = (const float*)d_in[3];
    const float* conv_w = (const float*)d_in[4]; // (3, 64, 64)
    const float* conv_b = (const float*)d_in[5]; // (3, 64)
    const float* w1     = (const float*)d_in[6];
    const float* b1     = (const float*)d_in[7];
    const float* w2     = (const float*)d_in[8];
    const float* b2     = (const float*)d_in[9];
    const float* w3     = (const float*)d_in[10];
    const float* b3     = (const float*)d_in[11];
    float* out = (float*)d_out;

    const int* row = eidx;
    const int* col = eidx + N_EDGES;

    // workspace layout (4-byte units)
    char* wsb = (char*)d_ws;
    size_t off = 0;
    auto alloc = [&](size_t elems) { void* p = wsb + off; off += ((elems * 4 + 255) & ~(size_t)255); return p; };
    int*   degi       = (int*)alloc(N_NODES);
    int*   scanned    = (int*)alloc(N_NODES);
    int*   bsums      = (int*)alloc(NB_SCAN);
    int*   boffs     = (int*)alloc(NB_SCAN);
    int*   bcur       = (int*)alloc(NBUCK);
    int*   row_start  = (int*)alloc(N_NODES);
    int*   cursor     = (int*)alloc(N_NODES);
    int*   sorted_row = (int*)alloc(N_EDGES);
    float* dinv       = (float*)alloc(N_NODES);
    float* h          = (float*)alloc((size_t)N_NODES * H);
    float* t          = (float*)alloc((size_t)N_NODES * H);
    float* sums       = (float*)alloc((size_t)N_GRAPHS * H);
    float* cnt        = (float*)alloc(N_GRAPHS);

    // staging (int2[N_EDGES] = 25.6 MB) aliases t (dead until k_linear of layer 0)
    int2* staging = (int2*)t;

    const int B = 256;
    const int gNH = (N_NODES * H + B - 1) / B;  // 25000
    const int gN  = (N_NODES + B - 1) / B;      // 391
    const int gE  = (N_EDGES + B - 1) / B;      // 12500
    const int gInitAll = ((N_GRAPHS * H > N_NODES ? N_GRAPHS * H : N_NODES) + B - 1) / B;
    const int gPool = ((N_NODES + 127) / 128 * 64 + B - 1) / B;  // 782 waves

    hipLaunchKernelGGL(k_init, dim3(gInitAll), dim3(B), 0, stream, degi, bcur, sums, cnt);
    hipLaunchKernelGGL(k_hist, dim3(gE), dim3(B), 0, stream, col, degi);
    hipLaunchKernelGGL(k_scan1, dim3(NB_SCAN), dim3(256), 0, stream, degi, scanned, bsums);
    hipLaunchKernelGGL(k_scan2, dim3(1), dim3(128), 0, stream, bsums, boffs);
    hipLaunchKernelGGL(k_scan3, dim3(gN), dim3(B), 0, stream, scanned, boffs, degi,
                       row_start, cursor, dinv);
    hipLaunchKernelGGL(k_binA, dim3(gE), dim3(B), 0, stream, row, col, row_start, bcur, staging);
    hipLaunchKernelGGL(k_binB, dim3(NBUCK), dim3(B), 0, stream, staging, row_start, cursor, sorted_row);
    hipLaunchKernelGGL(k_embed, dim3(gNH), dim3(B), 0, stream, x, emb, h);

    for (int layer = 0; layer < N_LAYERS; ++layer) {
        hipLaunchKernelGGL(k_linear, dim3((N_NODES + 3) / 4), dim3(B), 0, stream,
                           h, conv_w + (size_t)layer * H * H, dinv, t);
        hipLaunchKernelGGL(k_gather, dim3(gNH), dim3(B), 0, stream,
                           sorted_row, row_start, degi, t, dinv,
                           conv_b + (size_t)layer * H, h, layer);
    }

    hipLaunchKernelGGL(k_pool2, dim3(gPool), dim3(B), 0, stream, h, batch, sums, cnt);
    hipLaunchKernelGGL(k_mlp, dim3(N_GRAPHS), dim3(64), 0, stream,
                       sums, cnt, w1, b1, w2, b2, w3, b3, out);

    (void)in_sizes; (void)n_in; (void)out_size; (void)ws_size;
}

// Round 4
// 740.393 us; speedup vs baseline: 2.1911x; 2.1911x over previous
//
#include <hip/hip_runtime.h>

#define N_NODES 100000
#define N_EDGES 3200000
#define N_GRAPHS 2048
#define H 64
#define N_LAYERS 3

#define BUCK_BITS 7
#define BUCK_NODES (1 << BUCK_BITS)                          // 128 nodes / bucket
#define NBUCK ((N_NODES + BUCK_NODES - 1) / BUCK_NODES)      // 782

#define BHIST_BLOCKS 256
#define EDGES_PER_BHIST (N_EDGES / BHIST_BLOCKS)             // 12500
#define BINA_BLOCKS 128
#define EDGES_PER_BINA (N_EDGES / BINA_BLOCKS)               // 25000

// ---------------- kernels ----------------

// zero bucket counts, pooled sums, counts
__global__ void k_init(int* bcnt, float* sums, float* cnt) {
    int i = blockIdx.x * blockDim.x + threadIdx.x;
    if (i < NBUCK) bcnt[i] = 0;
    if (i < N_GRAPHS * H) sums[i] = 0.0f;
    if (i < N_GRAPHS) cnt[i] = 0.0f;
}

// bucket-level histogram with LDS pre-aggregation (782 counters)
__global__ void k_bhist(const int* __restrict__ col, int* __restrict__ bcnt) {
    __shared__ int lh[NBUCK];
    int tid = threadIdx.x;
    for (int i = tid; i < NBUCK; i += 256) lh[i] = 0;
    __syncthreads();
    int base = blockIdx.x * EDGES_PER_BHIST;
    for (int k = tid; k < EDGES_PER_BHIST; k += 256)
        atomicAdd(&lh[col[base + k] >> BUCK_BITS], 1);
    __syncthreads();
    for (int i = tid; i < NBUCK; i += 256)
        if (lh[i]) atomicAdd(&bcnt[i], lh[i]);
}

// scan the 782 bucket counts (single block, 1024 threads); init reservation cursors
__global__ void k_bscan(const int* __restrict__ bcnt, int* __restrict__ bbase,
                        int* __restrict__ bcur) {
    __shared__ int s[1024];
    int tid = threadIdx.x;
    int v = (tid < NBUCK) ? bcnt[tid] : 0;
    s[tid] = v;
    __syncthreads();
    for (int off = 1; off < 1024; off <<= 1) {
        int x = (tid >= off) ? s[tid - off] : 0;
        __syncthreads();
        s[tid] += x;
        __syncthreads();
    }
    if (tid < NBUCK) {
        int e = s[tid] - v;  // exclusive
        bbase[tid] = e;
        bcur[tid] = e;
    }
    if (tid == 0) bbase[NBUCK] = N_EDGES;
}

// pass A: per-block two-phase partition. LDS histogram -> bulk slice reservation
// (one global atomic per block-bucket) -> contiguous packed writes.
__global__ __launch_bounds__(1024) void k_binA(const int* __restrict__ row,
                                               const int* __restrict__ col,
                                               int* __restrict__ bcur,
                                               int* __restrict__ staging) {
    __shared__ int lcnt[NBUCK];
    __shared__ int lbase[NBUCK];
    int tid = threadIdx.x;
    int base = blockIdx.x * EDGES_PER_BINA;
    for (int i = tid; i < NBUCK; i += 1024) lcnt[i] = 0;
    __syncthreads();
    for (int k = tid; k < EDGES_PER_BINA; k += 1024)
        atomicAdd(&lcnt[col[base + k] >> BUCK_BITS], 1);
    __syncthreads();
    for (int i = tid; i < NBUCK; i += 1024) {
        int c = lcnt[i];
        lbase[i] = c ? atomicAdd(&bcur[i], c) : 0;
        lcnt[i] = 0;
    }
    __syncthreads();
    for (int k = tid; k < EDGES_PER_BINA; k += 1024) {
        int c = col[base + k];
        int b = c >> BUCK_BITS;
        int r = atomicAdd(&lcnt[b], 1);
        // pack: row (17 bits) | local node (7 bits)
        staging[lbase[b] + r] = row[base + k] | ((c & (BUCK_NODES - 1)) << 17);
    }
}

// pass B: one block per bucket. Local degree hist + scan in LDS -> degi/row_start/dinv,
// then finish the per-node sort within the L2-resident window.
__global__ void k_binB(const int* __restrict__ staging, const int* __restrict__ bbase,
                       int* __restrict__ sorted_row, int* __restrict__ degi,
                       int* __restrict__ row_start, float* __restrict__ dinv) {
    __shared__ int lde[BUCK_NODES];
    __shared__ int lsc[BUCK_NODES];
    int b = blockIdx.x, tid = threadIdx.x;
    int n0 = b << BUCK_BITS;
    int s0 = bbase[b], s1 = bbase[b + 1];
    if (tid < BUCK_NODES) lde[tid] = 0;
    __syncthreads();
    for (int i = s0 + tid; i < s1; i += 256)
        atomicAdd(&lde[staging[i] >> 17], 1);
    __syncthreads();
    if (tid < BUCK_NODES) lsc[tid] = lde[tid];
    __syncthreads();
    for (int off = 1; off < BUCK_NODES; off <<= 1) {
        int x = (tid >= off && tid < BUCK_NODES) ? lsc[tid - off] : 0;
        __syncthreads();
        if (tid < BUCK_NODES) lsc[tid] += x;
        __syncthreads();
    }
    if (tid < BUCK_NODES) {
        int n = n0 + tid;
        int excl = lsc[tid] - lde[tid];
        if (n < N_NODES) {
            row_start[n] = s0 + excl;
            degi[n] = lde[tid];
            dinv[n] = rsqrtf((float)(lde[tid] + 1));  // +1 self-loop
        }
        lsc[tid] = excl;
        lde[tid] = 0;  // reuse as rank counter
    }
    __syncthreads();
    for (int i = s0 + tid; i < s1; i += 256) {
        int p = staging[i];
        int ln = p >> 17;
        int r = atomicAdd(&lde[ln], 1);
        sorted_row[s0 + lsc[ln] + r] = p & 0x1FFFF;
    }
}

// h = emb[x]
__global__ void k_embed(const int* __restrict__ x, const float* __restrict__ emb,
                        float* __restrict__ h) {
    int i = blockIdx.x * blockDim.x + threadIdx.x;
    if (i >= N_NODES * H) return;
    int n = i >> 6, c = i & 63;
    h[i] = emb[x[n] * H + c];
}

// t' = dinv[n] * (h @ W)   (block = 4 nodes x 64 channels)
__global__ void k_linear(const float* __restrict__ h, const float* __restrict__ W,
                         const float* __restrict__ dinv, float* __restrict__ t) {
    __shared__ float sW[H * H];
    __shared__ float sh[4][H];
    int tid = threadIdx.x;
    for (int i = tid; i < H * H; i += 256) sW[i] = W[i];
    int r = tid >> 6, c = tid & 63;
    int n = blockIdx.x * 4 + r;
    sh[r][c] = (n < N_NODES) ? h[n * H + c] : 0.0f;
    __syncthreads();
    if (n < N_NODES) {
        float acc = 0.0f;
#pragma unroll
        for (int k = 0; k < H; ++k) acc += sh[r][k] * sW[k * H + c];
        t[n * H + c] = acc * dinv[n];
    }
}

// fused gather + finalize: one wave per node, lane = channel
__global__ void k_gather(const int* __restrict__ sorted_row, const int* __restrict__ row_start,
                         const int* __restrict__ degi, const float* __restrict__ t,
                         const float* __restrict__ dinv, const float* __restrict__ b,
                         float* __restrict__ h, int layer) {
    int gid = blockIdx.x * blockDim.x + threadIdx.x;
    int n = gid >> 6;
    int lane = gid & 63;
    if (n >= N_NODES) return;
    int start = row_start[n];
    int d = degi[n];
    float acc = t[n * H + lane];  // self-loop term
    int e = 0;
    for (; e + 4 <= d; e += 4) {
        int r0 = sorted_row[start + e + 0];
        int r1 = sorted_row[start + e + 1];
        int r2 = sorted_row[start + e + 2];
        int r3 = sorted_row[start + e + 3];
        float a0 = t[r0 * H + lane];
        float a1 = t[r1 * H + lane];
        float a2 = t[r2 * H + lane];
        float a3 = t[r3 * H + lane];
        acc += a0 + a1 + a2 + a3;
    }
    for (; e < d; ++e) acc += t[sorted_row[start + e] * H + lane];
    float v = fmaxf(acc * dinv[n] + b[lane], 0.0f);
    h[n * H + lane] = (layer == 0) ? v : h[n * H + lane] + v;
}

// segmented mean-pool: each wave owns 128 consecutive nodes (batch is sorted)
__global__ void k_pool2(const float* __restrict__ h, const int* __restrict__ batch,
                        float* __restrict__ sums, float* __restrict__ cnt) {
    const int CH = 128;
    int wave = (blockIdx.x * blockDim.x + threadIdx.x) >> 6;
    int lane = threadIdx.x & 63;
    int n0 = wave * CH;
    if (n0 >= N_NODES) return;
    int n1 = n0 + CH;
    if (n1 > N_NODES) n1 = N_NODES;
    int g_cur = batch[n0];
    float acc = 0.0f;
    int c = 0;
    for (int n = n0; n < n1; ++n) {
        int g = batch[n];
        if (g != g_cur) {
            atomicAdd(&sums[g_cur * H + lane], acc);
            if (lane == 0) atomicAdd(&cnt[g_cur], (float)c);
            acc = 0.0f; c = 0; g_cur = g;
        }
        acc += h[n * H + lane];
        ++c;
    }
    atomicAdd(&sums[g_cur * H + lane], acc);
    if (lane == 0) atomicAdd(&cnt[g_cur], (float)c);
}

// predictor MLP: one block (64 threads) per graph
__global__ void k_mlp(const float* __restrict__ sums, const float* __restrict__ cnt,
                      const float* __restrict__ w1, const float* __restrict__ b1,
                      const float* __restrict__ w2, const float* __restrict__ b2,
                      const float* __restrict__ w3, const float* __restrict__ b3,
                      float* __restrict__ out) {
    __shared__ float sg[H];
    __shared__ float s1[32];
    __shared__ float s2[16];
    int g = blockIdx.x, tid = threadIdx.x;
    float inv = 1.0f / fmaxf(cnt[g], 1.0f);
    sg[tid] = sums[g * H + tid] * inv;
    __syncthreads();
    if (tid < 32) {
        float acc = b1[tid];
#pragma unroll
        for (int k = 0; k < H; ++k) acc += sg[k] * w1[k * 32 + tid];
        s1[tid] = fmaxf(acc, 0.0f);
    }
    __syncthreads();
    if (tid < 16) {
        float acc = b2[tid];
#pragma unroll
        for (int k = 0; k < 32; ++k) acc += s1[k] * w2[k * 16 + tid];
        s2[tid] = fmaxf(acc, 0.0f);
    }
    __syncthreads();
    if (tid == 0) {
        float acc = b3[0];
#pragma unroll
        for (int k = 0; k < 16; ++k) acc += s2[k] * w3[k];
        out[g] = acc;
    }
}

// ---------------- launch ----------------

extern "C" void kernel_launch(void* const* d_in, const int* in_sizes, int n_in,
                              void* d_out, int out_size, void* d_ws, size_t ws_size,
                              hipStream_t stream) {
    const int*   x      = (const int*)d_in[0];
    const int*   eidx   = (const int*)d_in[1];   // (2, E): row = eidx, col = eidx + E
    const int*   batch  = (const int*)d_in[2];
    const float* emb    = (const float*)d_in[3];
    const float* conv_w = (const float*)d_in[4]; // (3, 64, 64)
    const float* conv_b = (const float*)d_in[5]; // (3, 64)
    const float* w1     = (const float*)d_in[6];
    const float* b1     = (const float*)d_in[7];
    const float* w2     = (const float*)d_in[8];
    const float* b2     = (const float*)d_in[9];
    const float* w3     = (const float*)d_in[10];
    const float* b3     = (const float*)d_in[11];
    float* out = (float*)d_out;

    const int* row = eidx;
    const int* col = eidx + N_EDGES;

    // workspace layout (4-byte units)
    char* wsb = (char*)d_ws;
    size_t off = 0;
    auto alloc = [&](size_t elems) { void* p = wsb + off; off += ((elems * 4 + 255) & ~(size_t)255); return p; };
    int*   bcnt       = (int*)alloc(NBUCK);
    int*   bbase      = (int*)alloc(NBUCK + 1);
    int*   bcur       = (int*)alloc(NBUCK);
    int*   row_start  = (int*)alloc(N_NODES);
    int*   degi       = (int*)alloc(N_NODES);
    float* dinv       = (float*)alloc(N_NODES);
    int*   sorted_row = (int*)alloc(N_EDGES);
    float* h          = (float*)alloc((size_t)N_NODES * H);
    float* t          = (float*)alloc((size_t)N_NODES * H);
    float* sums       = (float*)alloc((size_t)N_GRAPHS * H);
    float* cnt        = (float*)alloc(N_GRAPHS);

    // packed staging (int[N_EDGES] = 12.8 MB) aliases t (dead until k_linear layer 0)
    int* staging = (int*)t;

    const int B = 256;
    const int gNH = (N_NODES * H + B - 1) / B;  // 25000
    const int gInitAll = (N_GRAPHS * H + B - 1) / B;  // 512 (covers NBUCK, N_GRAPHS)
    const int gPool = ((N_NODES + 127) / 128 * 64 + B - 1) / B;

    hipLaunchKernelGGL(k_init, dim3(gInitAll), dim3(B), 0, stream, bcnt, sums, cnt);
    hipLaunchKernelGGL(k_bhist, dim3(BHIST_BLOCKS), dim3(256), 0, stream, col, bcnt);
    hipLaunchKernelGGL(k_bscan, dim3(1), dim3(1024), 0, stream, bcnt, bbase, bcur);
    hipLaunchKernelGGL(k_binA, dim3(BINA_BLOCKS), dim3(1024), 0, stream, row, col, bcur, staging);
    hipLaunchKernelGGL(k_binB, dim3(NBUCK), dim3(256), 0, stream, staging, bbase,
                       sorted_row, degi, row_start, dinv);
    hipLaunchKernelGGL(k_embed, dim3(gNH), dim3(B), 0, stream, x, emb, h);

    for (int layer = 0; layer < N_LAYERS; ++layer) {
        hipLaunchKernelGGL(k_linear, dim3((N_NODES + 3) / 4), dim3(B), 0, stream,
                           h, conv_w + (size_t)layer * H * H, dinv, t);
        hipLaunchKernelGGL(k_gather, dim3(gNH), dim3(B), 0, stream,
                           sorted_row, row_start, degi, t, dinv,
                           conv_b + (size_t)layer * H, h, layer);
    }

    hipLaunchKernelGGL(k_pool2, dim3(gPool), dim3(B), 0, stream, h, batch, sums, cnt);
    hipLaunchKernelGGL(k_mlp, dim3(N_GRAPHS), dim3(64), 0, stream,
                       sums, cnt, w1, b1, w2, b2, w3, b3, out);

    (void)in_sizes; (void)n_in; (void)out_size; (void)ws_size;
}

// Round 5
// 652.627 us; speedup vs baseline: 2.4858x; 1.1345x over previous
//
#include <hip/hip_runtime.h>

#define N_NODES 100000
#define N_EDGES 3200000
#define N_GRAPHS 2048
#define H 64
#define N_LAYERS 3

#define BUCK_BITS 7
#define BUCK_NODES (1 << BUCK_BITS)                          // 128 nodes / bucket
#define NBUCK ((N_NODES + BUCK_NODES - 1) / BUCK_NODES)      // 782

#define BHIST_BLOCKS 256
#define EDGES_PER_BHIST (N_EDGES / BHIST_BLOCKS)             // 12500
#define BINA_BLOCKS 128
#define EDGES_PER_BINA (N_EDGES / BINA_BLOCKS)               // 25000

#define LIN_NODES_PER_WAVE 32

// ---------------- kernels ----------------

// zero bucket counts, pooled sums, counts
__global__ void k_init(int* bcnt, float* sums, float* cnt) {
    int i = blockIdx.x * blockDim.x + threadIdx.x;
    if (i < NBUCK) bcnt[i] = 0;
    if (i < N_GRAPHS * H) sums[i] = 0.0f;
    if (i < N_GRAPHS) cnt[i] = 0.0f;
}

// bucket-level histogram with LDS pre-aggregation (782 counters)
__global__ void k_bhist(const int* __restrict__ col, int* __restrict__ bcnt) {
    __shared__ int lh[NBUCK];
    int tid = threadIdx.x;
    for (int i = tid; i < NBUCK; i += 256) lh[i] = 0;
    __syncthreads();
    int base = blockIdx.x * EDGES_PER_BHIST;
    for (int k = tid; k < EDGES_PER_BHIST; k += 256)
        atomicAdd(&lh[col[base + k] >> BUCK_BITS], 1);
    __syncthreads();
    for (int i = tid; i < NBUCK; i += 256)
        if (lh[i]) atomicAdd(&bcnt[i], lh[i]);
}

// scan the 782 bucket counts (single block, 1024 threads); init reservation cursors
__global__ void k_bscan(const int* __restrict__ bcnt, int* __restrict__ bbase,
                        int* __restrict__ bcur) {
    __shared__ int s[1024];
    int tid = threadIdx.x;
    int v = (tid < NBUCK) ? bcnt[tid] : 0;
    s[tid] = v;
    __syncthreads();
    for (int off = 1; off < 1024; off <<= 1) {
        int x = (tid >= off) ? s[tid - off] : 0;
        __syncthreads();
        s[tid] += x;
        __syncthreads();
    }
    if (tid < NBUCK) {
        int e = s[tid] - v;  // exclusive
        bbase[tid] = e;
        bcur[tid] = e;
    }
    if (tid == 0) bbase[NBUCK] = N_EDGES;
}

// pass A: per-block two-phase partition. LDS histogram -> bulk slice reservation
// (one global atomic per block-bucket) -> contiguous packed writes.
__global__ __launch_bounds__(1024) void k_binA(const int* __restrict__ row,
                                               const int* __restrict__ col,
                                               int* __restrict__ bcur,
                                               int* __restrict__ staging) {
    __shared__ int lcnt[NBUCK];
    __shared__ int lbase[NBUCK];
    int tid = threadIdx.x;
    int base = blockIdx.x * EDGES_PER_BINA;
    for (int i = tid; i < NBUCK; i += 1024) lcnt[i] = 0;
    __syncthreads();
    for (int k = tid; k < EDGES_PER_BINA; k += 1024)
        atomicAdd(&lcnt[col[base + k] >> BUCK_BITS], 1);
    __syncthreads();
    for (int i = tid; i < NBUCK; i += 1024) {
        int c = lcnt[i];
        lbase[i] = c ? atomicAdd(&bcur[i], c) : 0;
        lcnt[i] = 0;
    }
    __syncthreads();
    for (int k = tid; k < EDGES_PER_BINA; k += 1024) {
        int c = col[base + k];
        int b = c >> BUCK_BITS;
        int r = atomicAdd(&lcnt[b], 1);
        // pack: row (17 bits) | local node (7 bits)
        staging[lbase[b] + r] = row[base + k] | ((c & (BUCK_NODES - 1)) << 17);
    }
}

// pass B: one block per bucket. Local degree hist + scan in LDS -> degi/row_start/dinv,
// then finish the per-node sort within the L2-resident window.
__global__ void k_binB(const int* __restrict__ staging, const int* __restrict__ bbase,
                       int* __restrict__ sorted_row, int* __restrict__ degi,
                       int* __restrict__ row_start, float* __restrict__ dinv) {
    __shared__ int lde[BUCK_NODES];
    __shared__ int lsc[BUCK_NODES];
    int b = blockIdx.x, tid = threadIdx.x;
    int n0 = b << BUCK_BITS;
    int s0 = bbase[b], s1 = bbase[b + 1];
    if (tid < BUCK_NODES) lde[tid] = 0;
    __syncthreads();
    for (int i = s0 + tid; i < s1; i += 256)
        atomicAdd(&lde[staging[i] >> 17], 1);
    __syncthreads();
    if (tid < BUCK_NODES) lsc[tid] = lde[tid];
    __syncthreads();
    for (int off = 1; off < BUCK_NODES; off <<= 1) {
        int x = (tid >= off && tid < BUCK_NODES) ? lsc[tid - off] : 0;
        __syncthreads();
        if (tid < BUCK_NODES) lsc[tid] += x;
        __syncthreads();
    }
    if (tid < BUCK_NODES) {
        int n = n0 + tid;
        int excl = lsc[tid] - lde[tid];
        if (n < N_NODES) {
            row_start[n] = s0 + excl;
            degi[n] = lde[tid];
            dinv[n] = rsqrtf((float)(lde[tid] + 1));  // +1 self-loop
        }
        lsc[tid] = excl;
        lde[tid] = 0;  // reuse as rank counter
    }
    __syncthreads();
    for (int i = s0 + tid; i < s1; i += 256) {
        int p = staging[i];
        int ln = p >> 17;
        int r = atomicAdd(&lde[ln], 1);
        sorted_row[s0 + lsc[ln] + r] = p & 0x1FFFF;
    }
}

// t' = dinv[n] * (hin @ W), hin = xidx ? emb[xidx[n]] : h[n].
// One wave per 32 nodes. W column in 64 VGPRs; h-row reads are wave-uniform
// (readfirstlane) -> scalar loads; inner loop = 64 v_fmac (sgpr x vgpr).
__global__ __launch_bounds__(256) void k_linear(const float* __restrict__ hin,
                                                const int* __restrict__ xidx,
                                                const float* __restrict__ W,
                                                const float* __restrict__ dinv,
                                                float* __restrict__ t) {
    int lane = threadIdx.x & 63;
    int wid = (blockIdx.x * blockDim.x + threadIdx.x) >> 6;
    float wreg[H];
#pragma unroll
    for (int k = 0; k < H; ++k) wreg[k] = W[k * H + lane];  // coalesced; W is L2-hot
    int n0 = wid * LIN_NODES_PER_WAVE;
    if (n0 >= N_NODES) return;
    for (int i = 0; i < LIN_NODES_PER_WAVE; ++i) {
        int n = __builtin_amdgcn_readfirstlane(n0 + i);
        if (n >= N_NODES) break;
        const float* hr;
        if (xidx) {
            int xi = __builtin_amdgcn_readfirstlane(xidx[n]);
            hr = hin + (size_t)xi * H;
        } else {
            hr = hin + (size_t)n * H;
        }
        float acc = 0.0f;
#pragma unroll
        for (int k = 0; k < H; ++k) acc += hr[k] * wreg[k];
        t[(size_t)n * H + lane] = acc * dinv[n];
    }
}

// fused gather + finalize: one wave per node; 2 half-waves x float2 channels,
// 8 gather rows in flight.
__global__ void k_gather(const int* __restrict__ sorted_row, const int* __restrict__ row_start,
                         const int* __restrict__ degi, const float* __restrict__ t,
                         const float* __restrict__ dinv, const float* __restrict__ bias,
                         float* __restrict__ h, int layer) {
    int gid = blockIdx.x * blockDim.x + threadIdx.x;
    int n = gid >> 6;
    if (n >= N_NODES) return;
    int lane = threadIdx.x & 63;
    int half = lane >> 5;   // which edge parity this half-wave takes
    int sub = lane & 31;    // float2 index within the 64-channel row
    const float2* t2 = (const float2*)t;
    int start = row_start[n];
    int d = degi[n];
    float ax = 0.0f, ay = 0.0f;
    int e = half;
    for (; e + 6 < d; e += 8) {
        int r0 = sorted_row[start + e + 0];
        int r1 = sorted_row[start + e + 2];
        int r2 = sorted_row[start + e + 4];
        int r3 = sorted_row[start + e + 6];
        float2 a0 = t2[(size_t)r0 * 32 + sub];
        float2 a1 = t2[(size_t)r1 * 32 + sub];
        float2 a2 = t2[(size_t)r2 * 32 + sub];
        float2 a3 = t2[(size_t)r3 * 32 + sub];
        ax += a0.x + a1.x + a2.x + a3.x;
        ay += a0.y + a1.y + a2.y + a3.y;
    }
    for (; e < d; e += 2) {
        int r = sorted_row[start + e];
        float2 a = t2[(size_t)r * 32 + sub];
        ax += a.x; ay += a.y;
    }
    // combine the two half-waves (same channels, disjoint edges)
    ax += __shfl_xor(ax, 32, 64);
    ay += __shfl_xor(ay, 32, 64);
    if (half == 0) {
        float2 self = t2[(size_t)n * 32 + sub];
        ax += self.x; ay += self.y;
        float di = dinv[n];
        const float2* b2 = (const float2*)bias;
        float2 bb = b2[sub];
        float vx = fmaxf(ax * di + bb.x, 0.0f);
        float vy = fmaxf(ay * di + bb.y, 0.0f);
        float2* h2 = (float2*)h;
        if (layer != 0) {
            float2 hp = h2[(size_t)n * 32 + sub];
            vx += hp.x; vy += hp.y;
        }
        h2[(size_t)n * 32 + sub] = make_float2(vx, vy);
    }
}

// segmented mean-pool: each wave owns 128 consecutive nodes (batch is sorted)
__global__ void k_pool2(const float* __restrict__ h, const int* __restrict__ batch,
                        float* __restrict__ sums, float* __restrict__ cnt) {
    const int CH = 128;
    int wave = (blockIdx.x * blockDim.x + threadIdx.x) >> 6;
    int lane = threadIdx.x & 63;
    int n0 = wave * CH;
    if (n0 >= N_NODES) return;
    int n1 = n0 + CH;
    if (n1 > N_NODES) n1 = N_NODES;
    int g_cur = batch[n0];
    float acc = 0.0f;
    int c = 0;
    for (int n = n0; n < n1; ++n) {
        int g = batch[n];
        if (g != g_cur) {
            atomicAdd(&sums[g_cur * H + lane], acc);
            if (lane == 0) atomicAdd(&cnt[g_cur], (float)c);
            acc = 0.0f; c = 0; g_cur = g;
        }
        acc += h[(size_t)n * H + lane];
        ++c;
    }
    atomicAdd(&sums[g_cur * H + lane], acc);
    if (lane == 0) atomicAdd(&cnt[g_cur], (float)c);
}

// predictor MLP: one block (64 threads) per graph
__global__ void k_mlp(const float* __restrict__ sums, const float* __restrict__ cnt,
                      const float* __restrict__ w1, const float* __restrict__ b1,
                      const float* __restrict__ w2, const float* __restrict__ b2,
                      const float* __restrict__ w3, const float* __restrict__ b3,
                      float* __restrict__ out) {
    __shared__ float sg[H];
    __shared__ float s1[32];
    __shared__ float s2[16];
    int g = blockIdx.x, tid = threadIdx.x;
    float inv = 1.0f / fmaxf(cnt[g], 1.0f);
    sg[tid] = sums[g * H + tid] * inv;
    __syncthreads();
    if (tid < 32) {
        float acc = b1[tid];
#pragma unroll
        for (int k = 0; k < H; ++k) acc += sg[k] * w1[k * 32 + tid];
        s1[tid] = fmaxf(acc, 0.0f);
    }
    __syncthreads();
    if (tid < 16) {
        float acc = b2[tid];
#pragma unroll
        for (int k = 0; k < 32; ++k) acc += s1[k] * w2[k * 16 + tid];
        s2[tid] = fmaxf(acc, 0.0f);
    }
    __syncthreads();
    if (tid == 0) {
        float acc = b3[0];
#pragma unroll
        for (int k = 0; k < 16; ++k) acc += s2[k] * w3[k];
        out[g] = acc;
    }
}

// ---------------- launch ----------------

extern "C" void kernel_launch(void* const* d_in, const int* in_sizes, int n_in,
                              void* d_out, int out_size, void* d_ws, size_t ws_size,
                              hipStream_t stream) {
    const int*   x      = (const int*)d_in[0];
    const int*   eidx   = (const int*)d_in[1];   // (2, E): row = eidx, col = eidx + E
    const int*   batch  = (const int*)d_in[2];
    const float* emb    = (const float*)d_in[3];
    const float* conv_w = (const float*)d_in[4]; // (3, 64, 64)
    const float* conv_b = (const float*)d_in[5]; // (3, 64)
    const float* w1     = (const float*)d_in[6];
    const float* b1     = (const float*)d_in[7];
    const float* w2     = (const float*)d_in[8];
    const float* b2     = (const float*)d_in[9];
    const float* w3     = (const float*)d_in[10];
    const float* b3     = (const float*)d_in[11];
    float* out = (float*)d_out;

    const int* row = eidx;
    const int* col = eidx + N_EDGES;

    // workspace layout (4-byte units)
    char* wsb = (char*)d_ws;
    size_t off = 0;
    auto alloc = [&](size_t elems) { void* p = wsb + off; off += ((elems * 4 + 255) & ~(size_t)255); return p; };
    int*   bcnt       = (int*)alloc(NBUCK);
    int*   bbase      = (int*)alloc(NBUCK + 1);
    int*   bcur       = (int*)alloc(NBUCK);
    int*   row_start  = (int*)alloc(N_NODES);
    int*   degi       = (int*)alloc(N_NODES);
    float* dinv       = (float*)alloc(N_NODES);
    int*   sorted_row = (int*)alloc(N_EDGES);
    float* h          = (float*)alloc((size_t)N_NODES * H);
    float* t          = (float*)alloc((size_t)N_NODES * H);
    float* sums       = (float*)alloc((size_t)N_GRAPHS * H);
    float* cnt        = (float*)alloc(N_GRAPHS);

    // packed staging (int[N_EDGES] = 12.8 MB) aliases t (dead until k_linear layer 0)
    int* staging = (int*)t;

    const int B = 256;
    const int gNH = (N_NODES * H + B - 1) / B;         // 25000 (wave-per-node kernels)
    const int gInitAll = (N_GRAPHS * H + B - 1) / B;   // covers NBUCK, N_GRAPHS too
    const int gPool = ((N_NODES + 127) / 128 * 64 + B - 1) / B;
    const int gLin = ((N_NODES + LIN_NODES_PER_WAVE - 1) / LIN_NODES_PER_WAVE * 64 + B - 1) / B;

    hipLaunchKernelGGL(k_init, dim3(gInitAll), dim3(B), 0, stream, bcnt, sums, cnt);
    hipLaunchKernelGGL(k_bhist, dim3(BHIST_BLOCKS), dim3(256), 0, stream, col, bcnt);
    hipLaunchKernelGGL(k_bscan, dim3(1), dim3(1024), 0, stream, bcnt, bbase, bcur);
    hipLaunchKernelGGL(k_binA, dim3(BINA_BLOCKS), dim3(1024), 0, stream, row, col, bcur, staging);
    hipLaunchKernelGGL(k_binB, dim3(NBUCK), dim3(256), 0, stream, staging, bbase,
                       sorted_row, degi, row_start, dinv);

    for (int layer = 0; layer < N_LAYERS; ++layer) {
        // layer 0 reads the embedding table directly (embed fused away)
        hipLaunchKernelGGL(k_linear, dim3(gLin), dim3(B), 0, stream,
                           (layer == 0) ? emb : h, (layer == 0) ? x : (const int*)nullptr,
                           conv_w + (size_t)layer * H * H, dinv, t);
        hipLaunchKernelGGL(k_gather, dim3(gNH), dim3(B), 0, stream,
                           sorted_row, row_start, degi, t, dinv,
                           conv_b + (size_t)layer * H, h, layer);
    }

    hipLaunchKernelGGL(k_pool2, dim3(gPool), dim3(B), 0, stream, h, batch, sums, cnt);
    hipLaunchKernelGGL(k_mlp, dim3(N_GRAPHS), dim3(64), 0, stream,
                       sums, cnt, w1, b1, w2, b2, w3, b3, out);

    (void)in_sizes; (void)n_in; (void)out_size; (void)ws_size;
}

// Round 6
// 512.309 us; speedup vs baseline: 3.1666x; 1.2739x over previous
//
#include <hip/hip_runtime.h>

#define N_NODES 100000
#define N_EDGES 3200000
#define N_GRAPHS 2048
#define H 64
#define N_LAYERS 3

#define BUCK_BITS 7
#define BUCK_NODES (1 << BUCK_BITS)                          // 128 nodes / bucket
#define NBUCK ((N_NODES + BUCK_NODES - 1) / BUCK_NODES)      // 782

#define BHIST_BLOCKS 256
#define EDGES_PER_BHIST (N_EDGES / BHIST_BLOCKS)             // 12500
#define BINA_BLOCKS 128
#define EDGES_PER_BINA (N_EDGES / BINA_BLOCKS)               // 25000

#define LIN_NODES_PER_WAVE 32

// fp32 -> bf16 (round-to-nearest-even)
__device__ inline unsigned short f2bf(float f) {
    union { float f; unsigned u; } v; v.f = f;
    unsigned u = v.u;
    u += 0x7fffu + ((u >> 16) & 1u);
    return (unsigned short)(u >> 16);
}
__device__ inline float bfhi(unsigned p) {  // high bf16 of packed pair
    union { unsigned u; float f; } v; v.u = p & 0xffff0000u; return v.f;
}
__device__ inline float bflo(unsigned p) {  // low bf16 of packed pair
    union { unsigned u; float f; } v; v.u = p << 16; return v.f;
}

// ---------------- kernels ----------------

__global__ void k_init(int* bcnt, float* sums, float* cnt) {
    int i = blockIdx.x * blockDim.x + threadIdx.x;
    if (i < NBUCK) bcnt[i] = 0;
    if (i < N_GRAPHS * H) sums[i] = 0.0f;
    if (i < N_GRAPHS) cnt[i] = 0.0f;
}

// bucket-level histogram with LDS pre-aggregation (782 counters)
__global__ void k_bhist(const int* __restrict__ col, int* __restrict__ bcnt) {
    __shared__ int lh[NBUCK];
    int tid = threadIdx.x;
    for (int i = tid; i < NBUCK; i += 256) lh[i] = 0;
    __syncthreads();
    int base = blockIdx.x * EDGES_PER_BHIST;
    for (int k = tid; k < EDGES_PER_BHIST; k += 256)
        atomicAdd(&lh[col[base + k] >> BUCK_BITS], 1);
    __syncthreads();
    for (int i = tid; i < NBUCK; i += 256)
        if (lh[i]) atomicAdd(&bcnt[i], lh[i]);
}

// scan the 782 bucket counts; init reservation cursors
__global__ void k_bscan(const int* __restrict__ bcnt, int* __restrict__ bbase,
                        int* __restrict__ bcur) {
    __shared__ int s[1024];
    int tid = threadIdx.x;
    int v = (tid < NBUCK) ? bcnt[tid] : 0;
    s[tid] = v;
    __syncthreads();
    for (int off = 1; off < 1024; off <<= 1) {
        int x = (tid >= off) ? s[tid - off] : 0;
        __syncthreads();
        s[tid] += x;
        __syncthreads();
    }
    if (tid < NBUCK) {
        int e = s[tid] - v;
        bbase[tid] = e;
        bcur[tid] = e;
    }
    if (tid == 0) bbase[NBUCK] = N_EDGES;
}

// pass A: per-block two-phase partition (LDS hist -> bulk reservation -> packed writes)
__global__ __launch_bounds__(1024) void k_binA(const int* __restrict__ row,
                                               const int* __restrict__ col,
                                               int* __restrict__ bcur,
                                               int* __restrict__ staging) {
    __shared__ int lcnt[NBUCK];
    __shared__ int lbase[NBUCK];
    int tid = threadIdx.x;
    int base = blockIdx.x * EDGES_PER_BINA;
    for (int i = tid; i < NBUCK; i += 1024) lcnt[i] = 0;
    __syncthreads();
    for (int k = tid; k < EDGES_PER_BINA; k += 1024)
        atomicAdd(&lcnt[col[base + k] >> BUCK_BITS], 1);
    __syncthreads();
    for (int i = tid; i < NBUCK; i += 1024) {
        int c = lcnt[i];
        lbase[i] = c ? atomicAdd(&bcur[i], c) : 0;
        lcnt[i] = 0;
    }
    __syncthreads();
    for (int k = tid; k < EDGES_PER_BINA; k += 1024) {
        int c = col[base + k];
        int b = c >> BUCK_BITS;
        int r = atomicAdd(&lcnt[b], 1);
        staging[lbase[b] + r] = row[base + k] | ((c & (BUCK_NODES - 1)) << 17);
    }
}

// pass B: per-bucket degree hist/scan -> degi/row_start/dinv, then local sort
__global__ void k_binB(const int* __restrict__ staging, const int* __restrict__ bbase,
                       int* __restrict__ sorted_row, int* __restrict__ degi,
                       int* __restrict__ row_start, float* __restrict__ dinv) {
    __shared__ int lde[BUCK_NODES];
    __shared__ int lsc[BUCK_NODES];
    int b = blockIdx.x, tid = threadIdx.x;
    int n0 = b << BUCK_BITS;
    int s0 = bbase[b], s1 = bbase[b + 1];
    if (tid < BUCK_NODES) lde[tid] = 0;
    __syncthreads();
    for (int i = s0 + tid; i < s1; i += 256)
        atomicAdd(&lde[staging[i] >> 17], 1);
    __syncthreads();
    if (tid < BUCK_NODES) lsc[tid] = lde[tid];
    __syncthreads();
    for (int off = 1; off < BUCK_NODES; off <<= 1) {
        int x = (tid >= off && tid < BUCK_NODES) ? lsc[tid - off] : 0;
        __syncthreads();
        if (tid < BUCK_NODES) lsc[tid] += x;
        __syncthreads();
    }
    if (tid < BUCK_NODES) {
        int n = n0 + tid;
        int excl = lsc[tid] - lde[tid];
        if (n < N_NODES) {
            row_start[n] = s0 + excl;
            degi[n] = lde[tid];
            dinv[n] = rsqrtf((float)(lde[tid] + 1));
        }
        lsc[tid] = excl;
        lde[tid] = 0;
    }
    __syncthreads();
    for (int i = s0 + tid; i < s1; i += 256) {
        int p = staging[i];
        int ln = p >> 17;
        int r = atomicAdd(&lde[ln], 1);
        sorted_row[s0 + lsc[ln] + r] = p & 0x1FFFF;
    }
}

// t' = bf16( dinv[n] * (hin @ W) ), hin = xidx ? emb[xidx[n]] : h[n]
__global__ __launch_bounds__(256) void k_linear(const float* __restrict__ hin,
                                                const int* __restrict__ xidx,
                                                const float* __restrict__ W,
                                                const float* __restrict__ dinv,
                                                unsigned short* __restrict__ t) {
    int lane = threadIdx.x & 63;
    int wid = (blockIdx.x * blockDim.x + threadIdx.x) >> 6;
    float wreg[H];
#pragma unroll
    for (int k = 0; k < H; ++k) wreg[k] = W[k * H + lane];
    int n0 = wid * LIN_NODES_PER_WAVE;
    if (n0 >= N_NODES) return;
    for (int i = 0; i < LIN_NODES_PER_WAVE; ++i) {
        int n = __builtin_amdgcn_readfirstlane(n0 + i);
        if (n >= N_NODES) break;
        const float* hr;
        if (xidx) {
            int xi = __builtin_amdgcn_readfirstlane(xidx[n]);
            hr = hin + (size_t)xi * H;
        } else {
            hr = hin + (size_t)n * H;
        }
        float acc = 0.0f;
#pragma unroll
        for (int k = 0; k < H; ++k) acc += hr[k] * wreg[k];
        t[(size_t)n * H + lane] = f2bf(acc * dinv[n]);
    }
}

// fused gather + finalize: one wave per node; 2 half-waves, bf16x2 channels,
// 8 rows in flight per half-wave (16 per wave). fp32 accumulation.
__global__ void k_gather(const int* __restrict__ sorted_row, const int* __restrict__ row_start,
                         const int* __restrict__ degi, const unsigned short* __restrict__ t,
                         const float* __restrict__ dinv, const float* __restrict__ bias,
                         float* __restrict__ h, int layer) {
    int gid = blockIdx.x * blockDim.x + threadIdx.x;
    int n = gid >> 6;
    if (n >= N_NODES) return;
    int lane = threadIdx.x & 63;
    int half = lane >> 5;   // edge parity for this half-wave
    int sub = lane & 31;    // bf16x2 pair index within the 64-channel row
    const unsigned* t2 = (const unsigned*)t;  // 32 packed pairs per row
    int start = row_start[n];
    int d = degi[n];
    float ax = 0.0f, ay = 0.0f;
    int e = half;
    for (; e + 14 < d; e += 16) {
        unsigned p0 = t2[(size_t)sorted_row[start + e + 0] * 32 + sub];
        unsigned p1 = t2[(size_t)sorted_row[start + e + 2] * 32 + sub];
        unsigned p2 = t2[(size_t)sorted_row[start + e + 4] * 32 + sub];
        unsigned p3 = t2[(size_t)sorted_row[start + e + 6] * 32 + sub];
        unsigned p4 = t2[(size_t)sorted_row[start + e + 8] * 32 + sub];
        unsigned p5 = t2[(size_t)sorted_row[start + e + 10] * 32 + sub];
        unsigned p6 = t2[(size_t)sorted_row[start + e + 12] * 32 + sub];
        unsigned p7 = t2[(size_t)sorted_row[start + e + 14] * 32 + sub];
        ax += bflo(p0) + bflo(p1) + bflo(p2) + bflo(p3)
            + bflo(p4) + bflo(p5) + bflo(p6) + bflo(p7);
        ay += bfhi(p0) + bfhi(p1) + bfhi(p2) + bfhi(p3)
            + bfhi(p4) + bfhi(p5) + bfhi(p6) + bfhi(p7);
    }
    for (; e + 6 < d; e += 8) {
        unsigned p0 = t2[(size_t)sorted_row[start + e + 0] * 32 + sub];
        unsigned p1 = t2[(size_t)sorted_row[start + e + 2] * 32 + sub];
        unsigned p2 = t2[(size_t)sorted_row[start + e + 4] * 32 + sub];
        unsigned p3 = t2[(size_t)sorted_row[start + e + 6] * 32 + sub];
        ax += bflo(p0) + bflo(p1) + bflo(p2) + bflo(p3);
        ay += bfhi(p0) + bfhi(p1) + bfhi(p2) + bfhi(p3);
    }
    for (; e < d; e += 2) {
        unsigned p = t2[(size_t)sorted_row[start + e] * 32 + sub];
        ax += bflo(p); ay += bfhi(p);
    }
    ax += __shfl_xor(ax, 32, 64);
    ay += __shfl_xor(ay, 32, 64);
    if (half == 0) {
        unsigned self = t2[(size_t)n * 32 + sub];
        ax += bflo(self); ay += bfhi(self);
        float di = dinv[n];
        const float2* b2 = (const float2*)bias;
        float2 bb = b2[sub];
        float vx = fmaxf(ax * di + bb.x, 0.0f);
        float vy = fmaxf(ay * di + bb.y, 0.0f);
        float2* h2 = (float2*)h;
        if (layer != 0) {
            float2 hp = h2[(size_t)n * 32 + sub];
            vx += hp.x; vy += hp.y;
        }
        h2[(size_t)n * 32 + sub] = make_float2(vx, vy);
    }
}

// segmented mean-pool: each wave owns 128 consecutive nodes (batch is sorted)
__global__ void k_pool2(const float* __restrict__ h, const int* __restrict__ batch,
                        float* __restrict__ sums, float* __restrict__ cnt) {
    const int CH = 128;
    int wave = (blockIdx.x * blockDim.x + threadIdx.x) >> 6;
    int lane = threadIdx.x & 63;
    int n0 = wave * CH;
    if (n0 >= N_NODES) return;
    int n1 = n0 + CH;
    if (n1 > N_NODES) n1 = N_NODES;
    int g_cur = batch[n0];
    float acc = 0.0f;
    int c = 0;
    for (int n = n0; n < n1; ++n) {
        int g = batch[n];
        if (g != g_cur) {
            atomicAdd(&sums[g_cur * H + lane], acc);
            if (lane == 0) atomicAdd(&cnt[g_cur], (float)c);
            acc = 0.0f; c = 0; g_cur = g;
        }
        acc += h[(size_t)n * H + lane];
        ++c;
    }
    atomicAdd(&sums[g_cur * H + lane], acc);
    if (lane == 0) atomicAdd(&cnt[g_cur], (float)c);
}

// predictor MLP: one block (64 threads) per graph
__global__ void k_mlp(const float* __restrict__ sums, const float* __restrict__ cnt,
                      const float* __restrict__ w1, const float* __restrict__ b1,
                      const float* __restrict__ w2, const float* __restrict__ b2,
                      const float* __restrict__ w3, const float* __restrict__ b3,
                      float* __restrict__ out) {
    __shared__ float sg[H];
    __shared__ float s1[32];
    __shared__ float s2[16];
    int g = blockIdx.x, tid = threadIdx.x;
    float inv = 1.0f / fmaxf(cnt[g], 1.0f);
    sg[tid] = sums[g * H + tid] * inv;
    __syncthreads();
    if (tid < 32) {
        float acc = b1[tid];
#pragma unroll
        for (int k = 0; k < H; ++k) acc += sg[k] * w1[k * 32 + tid];
        s1[tid] = fmaxf(acc, 0.0f);
    }
    __syncthreads();
    if (tid < 16) {
        float acc = b2[tid];
#pragma unroll
        for (int k = 0; k < 32; ++k) acc += s1[k] * w2[k * 16 + tid];
        s2[tid] = fmaxf(acc, 0.0f);
    }
    __syncthreads();
    if (tid == 0) {
        float acc = b3[0];
#pragma unroll
        for (int k = 0; k < 16; ++k) acc += s2[k] * w3[k];
        out[g] = acc;
    }
}

// ---------------- launch ----------------

extern "C" void kernel_launch(void* const* d_in, const int* in_sizes, int n_in,
                              void* d_out, int out_size, void* d_ws, size_t ws_size,
                              hipStream_t stream) {
    const int*   x      = (const int*)d_in[0];
    const int*   eidx   = (const int*)d_in[1];   // (2, E): row = eidx, col = eidx + E
    const int*   batch  = (const int*)d_in[2];
    const float* emb    = (const float*)d_in[3];
    const float* conv_w = (const float*)d_in[4];
    const float* conv_b = (const float*)d_in[5];
    const float* w1     = (const float*)d_in[6];
    const float* b1     = (const float*)d_in[7];
    const float* w2     = (const float*)d_in[8];
    const float* b2     = (const float*)d_in[9];
    const float* w3     = (const float*)d_in[10];
    const float* b3     = (const float*)d_in[11];
    float* out = (float*)d_out;

    const int* row = eidx;
    const int* col = eidx + N_EDGES;

    // workspace layout (4-byte units)
    char* wsb = (char*)d_ws;
    size_t off = 0;
    auto alloc = [&](size_t elems) { void* p = wsb + off; off += ((elems * 4 + 255) & ~(size_t)255); return p; };
    int*   bcnt       = (int*)alloc(NBUCK);
    int*   bbase      = (int*)alloc(NBUCK + 1);
    int*   bcur       = (int*)alloc(NBUCK);
    int*   row_start  = (int*)alloc(N_NODES);
    int*   degi       = (int*)alloc(N_NODES);
    float* dinv       = (float*)alloc(N_NODES);
    int*   sorted_row = (int*)alloc(N_EDGES);
    float* h          = (float*)alloc((size_t)N_NODES * H);
    unsigned short* t = (unsigned short*)alloc((size_t)N_NODES * H / 2);  // bf16, 12.8 MB
    float* sums       = (float*)alloc((size_t)N_GRAPHS * H);
    float* cnt        = (float*)alloc(N_GRAPHS);

    // packed staging (int[N_EDGES] = 12.8 MB) aliases t (dead until k_linear layer 0)
    int* staging = (int*)t;

    const int B = 256;
    const int gNH = (N_NODES * H + B - 1) / B;
    const int gInitAll = (N_GRAPHS * H + B - 1) / B;
    const int gPool = ((N_NODES + 127) / 128 * 64 + B - 1) / B;
    const int gLin = ((N_NODES + LIN_NODES_PER_WAVE - 1) / LIN_NODES_PER_WAVE * 64 + B - 1) / B;

    hipLaunchKernelGGL(k_init, dim3(gInitAll), dim3(B), 0, stream, bcnt, sums, cnt);
    hipLaunchKernelGGL(k_bhist, dim3(BHIST_BLOCKS), dim3(256), 0, stream, col, bcnt);
    hipLaunchKernelGGL(k_bscan, dim3(1), dim3(1024), 0, stream, bcnt, bbase, bcur);
    hipLaunchKernelGGL(k_binA, dim3(BINA_BLOCKS), dim3(1024), 0, stream, row, col, bcur, staging);
    hipLaunchKernelGGL(k_binB, dim3(NBUCK), dim3(256), 0, stream, staging, bbase,
                       sorted_row, degi, row_start, dinv);

    for (int layer = 0; layer < N_LAYERS; ++layer) {
        hipLaunchKernelGGL(k_linear, dim3(gLin), dim3(B), 0, stream,
                           (layer == 0) ? emb : h, (layer == 0) ? x : (const int*)nullptr,
                           conv_w + (size_t)layer * H * H, dinv, t);
        hipLaunchKernelGGL(k_gather, dim3(gNH), dim3(B), 0, stream,
                           sorted_row, row_start, degi, t, dinv,
                           conv_b + (size_t)layer * H, h, layer);
    }

    hipLaunchKernelGGL(k_pool2, dim3(gPool), dim3(B), 0, stream, h, batch, sums, cnt);
    hipLaunchKernelGGL(k_mlp, dim3(N_GRAPHS), dim3(64), 0, stream,
                       sums, cnt, w1, b1, w2, b2, w3, b3, out);

    (void)in_sizes; (void)n_in; (void)out_size; (void)ws_size;
}

// Round 7
// 489.379 us; speedup vs baseline: 3.3150x; 1.0469x over previous
//
#include <hip/hip_runtime.h>

#define N_NODES 100000
#define N_EDGES 3200000
#define N_GRAPHS 2048
#define H 64
#define N_LAYERS 3

#define BUCK_BITS 7
#define BUCK_NODES (1 << BUCK_BITS)                          // 128 nodes / bucket
#define NBUCK ((N_NODES + BUCK_NODES - 1) / BUCK_NODES)      // 782

#define PART_BLOCKS 256
#define EDGES_PER_PART (N_EDGES / PART_BLOCKS)               // 12500

#define LIN_NODES_PER_WAVE 32

// fp32 -> bf16 (round-to-nearest-even)
__device__ inline unsigned short f2bf(float f) {
    union { float f; unsigned u; } v; v.f = f;
    unsigned u = v.u;
    u += 0x7fffu + ((u >> 16) & 1u);
    return (unsigned short)(u >> 16);
}
__device__ inline float bfhi(unsigned p) {
    union { unsigned u; float f; } v; v.u = p & 0xffff0000u; return v.f;
}
__device__ inline float bflo(unsigned p) {
    union { unsigned u; float f; } v; v.u = p << 16; return v.f;
}

// ---------------- kernels ----------------

__global__ void k_init(int* bcnt) {
    int i = blockIdx.x * blockDim.x + threadIdx.x;
    if (i < NBUCK) bcnt[i] = 0;
}

// bucket histogram; also store per-block rows for binA reuse
__global__ void k_bhist(const int* __restrict__ col, int* __restrict__ bcnt,
                        int* __restrict__ blkhist) {
    __shared__ int lh[NBUCK];
    int tid = threadIdx.x;
    for (int i = tid; i < NBUCK; i += 256) lh[i] = 0;
    __syncthreads();
    int base = blockIdx.x * EDGES_PER_PART;
    for (int k = tid; k < EDGES_PER_PART; k += 256)
        atomicAdd(&lh[col[base + k] >> BUCK_BITS], 1);
    __syncthreads();
    int* myhist = blkhist + (size_t)blockIdx.x * NBUCK;
    for (int i = tid; i < NBUCK; i += 256) {
        int c = lh[i];
        myhist[i] = c;
        if (c) atomicAdd(&bcnt[i], c);
    }
}

// scan the 782 bucket counts; init reservation cursors
__global__ void k_bscan(const int* __restrict__ bcnt, int* __restrict__ bbase,
                        int* __restrict__ bcur) {
    __shared__ int s[1024];
    int tid = threadIdx.x;
    int v = (tid < NBUCK) ? bcnt[tid] : 0;
    s[tid] = v;
    __syncthreads();
    for (int off = 1; off < 1024; off <<= 1) {
        int x = (tid >= off) ? s[tid - off] : 0;
        __syncthreads();
        s[tid] += x;
        __syncthreads();
    }
    if (tid < NBUCK) {
        int e = s[tid] - v;
        bbase[tid] = e;
        bcur[tid] = e;
    }
    if (tid == 0) bbase[NBUCK] = N_EDGES;
}

// pass A: slice reservation from precomputed block hist, then rank + packed write
__global__ __launch_bounds__(1024) void k_binA(const int* __restrict__ row,
                                               const int* __restrict__ col,
                                               const int* __restrict__ blkhist,
                                               int* __restrict__ bcur,
                                               int* __restrict__ staging) {
    __shared__ int lcnt[NBUCK];
    __shared__ int lbase[NBUCK];
    int tid = threadIdx.x;
    int base = blockIdx.x * EDGES_PER_PART;
    const int* myhist = blkhist + (size_t)blockIdx.x * NBUCK;
    for (int i = tid; i < NBUCK; i += 1024) {
        int c = myhist[i];
        lbase[i] = c ? atomicAdd(&bcur[i], c) : 0;
        lcnt[i] = 0;
    }
    __syncthreads();
    for (int k = tid; k < EDGES_PER_PART; k += 1024) {
        int c = col[base + k];
        int b = c >> BUCK_BITS;
        int r = atomicAdd(&lcnt[b], 1);
        staging[lbase[b] + r] = row[base + k] | ((c & (BUCK_NODES - 1)) << 17);
    }
}

// pass B: per-bucket degree hist/scan -> degi/row_start/dinv, then local sort
__global__ void k_binB(const int* __restrict__ staging, const int* __restrict__ bbase,
                       int* __restrict__ sorted_row, int* __restrict__ degi,
                       int* __restrict__ row_start, float* __restrict__ dinv) {
    __shared__ int lde[BUCK_NODES];
    __shared__ int lsc[BUCK_NODES];
    int b = blockIdx.x, tid = threadIdx.x;
    int n0 = b << BUCK_BITS;
    int s0 = bbase[b], s1 = bbase[b + 1];
    if (tid < BUCK_NODES) lde[tid] = 0;
    __syncthreads();
    for (int i = s0 + tid; i < s1; i += 256)
        atomicAdd(&lde[staging[i] >> 17], 1);
    __syncthreads();
    if (tid < BUCK_NODES) lsc[tid] = lde[tid];
    __syncthreads();
    for (int off = 1; off < BUCK_NODES; off <<= 1) {
        int x = (tid >= off && tid < BUCK_NODES) ? lsc[tid - off] : 0;
        __syncthreads();
        if (tid < BUCK_NODES) lsc[tid] += x;
        __syncthreads();
    }
    if (tid < BUCK_NODES) {
        int n = n0 + tid;
        int excl = lsc[tid] - lde[tid];
        if (n < N_NODES) {
            row_start[n] = s0 + excl;
            degi[n] = lde[tid];
            dinv[n] = rsqrtf((float)(lde[tid] + 1));
        }
        lsc[tid] = excl;
        lde[tid] = 0;
    }
    __syncthreads();
    for (int i = s0 + tid; i < s1; i += 256) {
        int p = staging[i];
        int ln = p >> 17;
        int r = atomicAdd(&lde[ln], 1);
        sorted_row[s0 + lsc[ln] + r] = p & 0x1FFFF;
    }
}

// t' = bf16( dinv[n] * (hin @ W) ), hin = xidx ? emb[xidx[n]] : h[n]
__global__ __launch_bounds__(256) void k_linear(const float* __restrict__ hin,
                                                const int* __restrict__ xidx,
                                                const float* __restrict__ W,
                                                const float* __restrict__ dinv,
                                                unsigned short* __restrict__ t) {
    int lane = threadIdx.x & 63;
    int wid = (blockIdx.x * blockDim.x + threadIdx.x) >> 6;
    float wreg[H];
#pragma unroll
    for (int k = 0; k < H; ++k) wreg[k] = W[k * H + lane];
    int n0 = wid * LIN_NODES_PER_WAVE;
    if (n0 >= N_NODES) return;
    for (int i = 0; i < LIN_NODES_PER_WAVE; ++i) {
        int n = __builtin_amdgcn_readfirstlane(n0 + i);
        if (n >= N_NODES) break;
        const float* hr;
        if (xidx) {
            int xi = __builtin_amdgcn_readfirstlane(xidx[n]);
            hr = hin + (size_t)xi * H;
        } else {
            hr = hin + (size_t)n * H;
        }
        float acc = 0.0f;
#pragma unroll
        for (int k = 0; k < H; ++k) acc += hr[k] * wreg[k];
        t[(size_t)n * H + lane] = f2bf(acc * dinv[n]);
    }
}

// fused gather + finalize: one wave per node; 2 half-waves, bf16x2 channels,
// up to 16 rows in flight per half-wave (32 edges/wave batch). fp32 accumulation.
__global__ void k_gather(const int* __restrict__ sorted_row, const int* __restrict__ row_start,
                         const int* __restrict__ degi, const unsigned short* __restrict__ t,
                         const float* __restrict__ dinv, const float* __restrict__ bias,
                         float* __restrict__ h, int layer) {
    int gid = blockIdx.x * blockDim.x + threadIdx.x;
    int n = gid >> 6;
    if (n >= N_NODES) return;
    int lane = threadIdx.x & 63;
    int half = lane >> 5;
    int sub = lane & 31;
    const unsigned* t2 = (const unsigned*)t;
    int start = row_start[n];
    int d = degi[n];
    float ax = 0.0f, ay = 0.0f;
    int e = half;
    for (; e + 30 < d; e += 32) {
        unsigned p[16];
#pragma unroll
        for (int j = 0; j < 16; ++j)
            p[j] = t2[(size_t)sorted_row[start + e + 2 * j] * 32 + sub];
#pragma unroll
        for (int j = 0; j < 16; ++j) { ax += bflo(p[j]); ay += bfhi(p[j]); }
    }
    for (; e + 14 < d; e += 16) {
        unsigned p[8];
#pragma unroll
        for (int j = 0; j < 8; ++j)
            p[j] = t2[(size_t)sorted_row[start + e + 2 * j] * 32 + sub];
#pragma unroll
        for (int j = 0; j < 8; ++j) { ax += bflo(p[j]); ay += bfhi(p[j]); }
    }
    for (; e + 6 < d; e += 8) {
        unsigned p[4];
#pragma unroll
        for (int j = 0; j < 4; ++j)
            p[j] = t2[(size_t)sorted_row[start + e + 2 * j] * 32 + sub];
#pragma unroll
        for (int j = 0; j < 4; ++j) { ax += bflo(p[j]); ay += bfhi(p[j]); }
    }
    for (; e < d; e += 2) {
        unsigned p = t2[(size_t)sorted_row[start + e] * 32 + sub];
        ax += bflo(p); ay += bfhi(p);
    }
    ax += __shfl_xor(ax, 32, 64);
    ay += __shfl_xor(ay, 32, 64);
    if (half == 0) {
        unsigned self = t2[(size_t)n * 32 + sub];
        ax += bflo(self); ay += bfhi(self);
        float di = dinv[n];
        const float2* b2 = (const float2*)bias;
        float2 bb = b2[sub];
        float vx = fmaxf(ax * di + bb.x, 0.0f);
        float vy = fmaxf(ay * di + bb.y, 0.0f);
        float2* h2 = (float2*)h;
        if (layer != 0) {
            float2 hp = h2[(size_t)n * 32 + sub];
            vx += hp.x; vy += hp.y;
        }
        h2[(size_t)n * 32 + sub] = make_float2(vx, vy);
    }
}

// fused mean-pool + MLP: one wave per graph. batch is sorted -> binary-search the
// node range; no atomics, no zeroed scratch.
__global__ void k_poolmlp(const float* __restrict__ h, const int* __restrict__ batch,
                          const float* __restrict__ w1, const float* __restrict__ b1,
                          const float* __restrict__ w2, const float* __restrict__ b2,
                          const float* __restrict__ w3, const float* __restrict__ b3,
                          float* __restrict__ out) {
    __shared__ float sg[H];
    __shared__ float s1[32];
    __shared__ float s2[16];
    int g = blockIdx.x, tid = threadIdx.x;
    // lower_bound(batch, g) and lower_bound(batch, g+1)
    int lo = 0, hi = N_NODES;
    while (lo < hi) { int mid = (lo + hi) >> 1; if (batch[mid] < g) lo = mid + 1; else hi = mid; }
    int lo2 = lo, hi2 = N_NODES;
    while (lo2 < hi2) { int mid = (lo2 + hi2) >> 1; if (batch[mid] < g + 1) lo2 = mid + 1; else hi2 = mid; }
    float acc = 0.0f;
    for (int n = lo; n < lo2; ++n) acc += h[(size_t)n * H + tid];
    float cntf = (float)(lo2 - lo);
    sg[tid] = acc / fmaxf(cntf, 1.0f);
    __syncthreads();
    if (tid < 32) {
        float a = b1[tid];
#pragma unroll
        for (int k = 0; k < H; ++k) a += sg[k] * w1[k * 32 + tid];
        s1[tid] = fmaxf(a, 0.0f);
    }
    __syncthreads();
    if (tid < 16) {
        float a = b2[tid];
#pragma unroll
        for (int k = 0; k < 32; ++k) a += s1[k] * w2[k * 16 + tid];
        s2[tid] = fmaxf(a, 0.0f);
    }
    __syncthreads();
    if (tid == 0) {
        float a = b3[0];
#pragma unroll
        for (int k = 0; k < 16; ++k) a += s2[k] * w3[k];
        out[g] = a;
    }
}

// ---------------- launch ----------------

extern "C" void kernel_launch(void* const* d_in, const int* in_sizes, int n_in,
                              void* d_out, int out_size, void* d_ws, size_t ws_size,
                              hipStream_t stream) {
    const int*   x      = (const int*)d_in[0];
    const int*   eidx   = (const int*)d_in[1];   // (2, E): row = eidx, col = eidx + E
    const int*   batch  = (const int*)d_in[2];
    const float* emb    = (const float*)d_in[3];
    const float* conv_w = (const float*)d_in[4];
    const float* conv_b = (const float*)d_in[5];
    const float* w1     = (const float*)d_in[6];
    const float* b1     = (const float*)d_in[7];
    const float* w2     = (const float*)d_in[8];
    const float* b2     = (const float*)d_in[9];
    const float* w3     = (const float*)d_in[10];
    const float* b3     = (const float*)d_in[11];
    float* out = (float*)d_out;

    const int* row = eidx;
    const int* col = eidx + N_EDGES;

    // workspace layout (4-byte units)
    char* wsb = (char*)d_ws;
    size_t off = 0;
    auto alloc = [&](size_t elems) { void* p = wsb + off; off += ((elems * 4 + 255) & ~(size_t)255); return p; };
    int*   bcnt       = (int*)alloc(NBUCK);
    int*   bbase      = (int*)alloc(NBUCK + 1);
    int*   bcur       = (int*)alloc(NBUCK);
    int*   blkhist    = (int*)alloc((size_t)PART_BLOCKS * NBUCK);
    int*   row_start  = (int*)alloc(N_NODES);
    int*   degi       = (int*)alloc(N_NODES);
    float* dinv       = (float*)alloc(N_NODES);
    int*   sorted_row = (int*)alloc(N_EDGES);
    float* h          = (float*)alloc((size_t)N_NODES * H);
    unsigned short* t = (unsigned short*)alloc((size_t)N_NODES * H / 2);  // bf16, 12.8 MB

    // packed staging (int[N_EDGES] = 12.8 MB) aliases t (dead until k_linear layer 0)
    int* staging = (int*)t;

    const int B = 256;
    const int gNH = (N_NODES * H + B - 1) / B;
    const int gLin = ((N_NODES + LIN_NODES_PER_WAVE - 1) / LIN_NODES_PER_WAVE * 64 + B - 1) / B;

    hipLaunchKernelGGL(k_init, dim3((NBUCK + B - 1) / B), dim3(B), 0, stream, bcnt);
    hipLaunchKernelGGL(k_bhist, dim3(PART_BLOCKS), dim3(256), 0, stream, col, bcnt, blkhist);
    hipLaunchKernelGGL(k_bscan, dim3(1), dim3(1024), 0, stream, bcnt, bbase, bcur);
    hipLaunchKernelGGL(k_binA, dim3(PART_BLOCKS), dim3(1024), 0, stream,
                       row, col, blkhist, bcur, staging);
    hipLaunchKernelGGL(k_binB, dim3(NBUCK), dim3(256), 0, stream, staging, bbase,
                       sorted_row, degi, row_start, dinv);

    for (int layer = 0; layer < N_LAYERS; ++layer) {
        hipLaunchKernelGGL(k_linear, dim3(gLin), dim3(B), 0, stream,
                           (layer == 0) ? emb : h, (layer == 0) ? x : (const int*)nullptr,
                           conv_w + (size_t)layer * H * H, dinv, t);
        hipLaunchKernelGGL(k_gather, dim3(gNH), dim3(B), 0, stream,
                           sorted_row, row_start, degi, t, dinv,
                           conv_b + (size_t)layer * H, h, layer);
    }

    hipLaunchKernelGGL(k_poolmlp, dim3(N_GRAPHS), dim3(64), 0, stream,
                       h, batch, w1, b1, w2, b2, w3, b3, out);

    (void)in_sizes; (void)n_in; (void)out_size; (void)ws_size;
}

// Round 8
// 488.329 us; speedup vs baseline: 3.3221x; 1.0022x over previous
//
#include <hip/hip_runtime.h>

#define N_NODES 100000
#define N_EDGES 3200000
#define N_GRAPHS 2048
#define VOCAB 92
#define H 64
#define N_LAYERS 3

#define BUCK_BITS 7
#define BUCK_NODES (1 << BUCK_BITS)                          // 128 nodes / bucket
#define NBUCK ((N_NODES + BUCK_NODES - 1) / BUCK_NODES)      // 782

#define PART_BLOCKS 256
#define EDGES_PER_PART (N_EDGES / PART_BLOCKS)               // 12500

#define LIN_NODES_PER_WAVE 32

// fp32 -> bf16 (round-to-nearest-even)
__device__ inline unsigned short f2bf(float f) {
    union { float f; unsigned u; } v; v.f = f;
    unsigned u = v.u;
    u += 0x7fffu + ((u >> 16) & 1u);
    return (unsigned short)(u >> 16);
}
__device__ inline float bfhi(unsigned p) {
    union { unsigned u; float f; } v; v.u = p & 0xffff0000u; return v.f;
}
__device__ inline float bflo(unsigned p) {
    union { unsigned u; float f; } v; v.u = p << 16; return v.f;
}

// ---------------- kernels ----------------

__global__ void k_init(int* bcnt) {
    int i = blockIdx.x * blockDim.x + threadIdx.x;
    if (i < NBUCK) bcnt[i] = 0;
}

// bucket histogram; also store per-block rows for binA reuse
__global__ void k_bhist(const int* __restrict__ col, int* __restrict__ bcnt,
                        int* __restrict__ blkhist) {
    __shared__ int lh[NBUCK];
    int tid = threadIdx.x;
    for (int i = tid; i < NBUCK; i += 256) lh[i] = 0;
    __syncthreads();
    int base = blockIdx.x * EDGES_PER_PART;
    for (int k = tid; k < EDGES_PER_PART; k += 256)
        atomicAdd(&lh[col[base + k] >> BUCK_BITS], 1);
    __syncthreads();
    int* myhist = blkhist + (size_t)blockIdx.x * NBUCK;
    for (int i = tid; i < NBUCK; i += 256) {
        int c = lh[i];
        myhist[i] = c;
        if (c) atomicAdd(&bcnt[i], c);
    }
}

// scan the 782 bucket counts; init reservation cursors
__global__ void k_bscan(const int* __restrict__ bcnt, int* __restrict__ bbase,
                        int* __restrict__ bcur) {
    __shared__ int s[1024];
    int tid = threadIdx.x;
    int v = (tid < NBUCK) ? bcnt[tid] : 0;
    s[tid] = v;
    __syncthreads();
    for (int off = 1; off < 1024; off <<= 1) {
        int x = (tid >= off) ? s[tid - off] : 0;
        __syncthreads();
        s[tid] += x;
        __syncthreads();
    }
    if (tid < NBUCK) {
        int e = s[tid] - v;
        bbase[tid] = e;
        bcur[tid] = e;
    }
    if (tid == 0) bbase[NBUCK] = N_EDGES;
}

// pass A: slice reservation from precomputed block hist, then rank + packed write
__global__ __launch_bounds__(1024) void k_binA(const int* __restrict__ row,
                                               const int* __restrict__ col,
                                               const int* __restrict__ blkhist,
                                               int* __restrict__ bcur,
                                               int* __restrict__ staging) {
    __shared__ int lcnt[NBUCK];
    __shared__ int lbase[NBUCK];
    int tid = threadIdx.x;
    int base = blockIdx.x * EDGES_PER_PART;
    const int* myhist = blkhist + (size_t)blockIdx.x * NBUCK;
    for (int i = tid; i < NBUCK; i += 1024) {
        int c = myhist[i];
        lbase[i] = c ? atomicAdd(&bcur[i], c) : 0;
        lcnt[i] = 0;
    }
    __syncthreads();
    for (int k = tid; k < EDGES_PER_PART; k += 1024) {
        int c = col[base + k];
        int b = c >> BUCK_BITS;
        int r = atomicAdd(&lcnt[b], 1);
        staging[lbase[b] + r] = row[base + k] | ((c & (BUCK_NODES - 1)) << 17);
    }
}

// pass B: per-bucket degree hist/scan -> degi/row_start/dinv + packed (x,dinv_bf16),
// then local sort
__global__ void k_binB(const int* __restrict__ staging, const int* __restrict__ bbase,
                       const int* __restrict__ x,
                       int* __restrict__ sorted_row, int* __restrict__ degi,
                       int* __restrict__ row_start, float* __restrict__ dinv,
                       unsigned* __restrict__ packed) {
    __shared__ int lde[BUCK_NODES];
    __shared__ int lsc[BUCK_NODES];
    int b = blockIdx.x, tid = threadIdx.x;
    int n0 = b << BUCK_BITS;
    int s0 = bbase[b], s1 = bbase[b + 1];
    if (tid < BUCK_NODES) lde[tid] = 0;
    __syncthreads();
    for (int i = s0 + tid; i < s1; i += 256)
        atomicAdd(&lde[staging[i] >> 17], 1);
    __syncthreads();
    if (tid < BUCK_NODES) lsc[tid] = lde[tid];
    __syncthreads();
    for (int off = 1; off < BUCK_NODES; off <<= 1) {
        int v = (tid >= off && tid < BUCK_NODES) ? lsc[tid - off] : 0;
        __syncthreads();
        if (tid < BUCK_NODES) lsc[tid] += v;
        __syncthreads();
    }
    if (tid < BUCK_NODES) {
        int n = n0 + tid;
        int excl = lsc[tid] - lde[tid];
        if (n < N_NODES) {
            row_start[n] = s0 + excl;
            degi[n] = lde[tid];
            float dv = rsqrtf((float)(lde[tid] + 1));
            dinv[n] = dv;
            packed[n] = ((unsigned)f2bf(dv) << 16) | (unsigned)x[n];
        }
        lsc[tid] = excl;
        lde[tid] = 0;
    }
    __syncthreads();
    for (int i = s0 + tid; i < s1; i += 256) {
        int p = staging[i];
        int ln = p >> 17;
        int r = atomicAdd(&lde[ln], 1);
        sorted_row[s0 + lsc[ln] + r] = p & 0x1FFFF;
    }
}

// M = emb @ W0 (92 x 64, f32). One block (64 threads) per vocab row.
__global__ void k_premix(const float* __restrict__ emb, const float* __restrict__ W0,
                         float* __restrict__ M) {
    int v = blockIdx.x, c = threadIdx.x;
    float acc = 0.0f;
#pragma unroll
    for (int k = 0; k < H; ++k) acc += emb[v * H + k] * W0[k * H + c];
    M[v * H + c] = acc;
}

// layer-0 gather: acc[n] = sum_e dinv_bf16[r] * M[x[r]]  (M in LDS, f32)
__global__ __launch_bounds__(256) void k_gather0(const int* __restrict__ sorted_row,
                                                 const int* __restrict__ row_start,
                                                 const int* __restrict__ degi,
                                                 const unsigned* __restrict__ packed,
                                                 const float* __restrict__ M,
                                                 const float* __restrict__ dinv,
                                                 const float* __restrict__ bias,
                                                 float* __restrict__ h) {
    __shared__ float Ml[VOCAB * H];
    int tid = threadIdx.x;
    for (int i = tid; i < VOCAB * H; i += 256) Ml[i] = M[i];
    __syncthreads();
    int gid = blockIdx.x * blockDim.x + tid;
    int n = gid >> 6;
    if (n >= N_NODES) return;
    int lane = tid & 63;
    int half = lane >> 5;
    int sub = lane & 31;
    const float2* M2 = (const float2*)Ml;
    int start = row_start[n];
    int d = degi[n];
    float ax = 0.0f, ay = 0.0f;
    int e = half;
    for (; e + 14 < d; e += 16) {
        unsigned p[8];
#pragma unroll
        for (int j = 0; j < 8; ++j)
            p[j] = packed[sorted_row[start + e + 2 * j]];
#pragma unroll
        for (int j = 0; j < 8; ++j) {
            float dv = __uint_as_float(p[j] & 0xffff0000u);
            float2 m = M2[(p[j] & 127u) * 32 + sub];
            ax += dv * m.x; ay += dv * m.y;
        }
    }
    for (; e + 6 < d; e += 8) {
        unsigned p[4];
#pragma unroll
        for (int j = 0; j < 4; ++j)
            p[j] = packed[sorted_row[start + e + 2 * j]];
#pragma unroll
        for (int j = 0; j < 4; ++j) {
            float dv = __uint_as_float(p[j] & 0xffff0000u);
            float2 m = M2[(p[j] & 127u) * 32 + sub];
            ax += dv * m.x; ay += dv * m.y;
        }
    }
    for (; e < d; e += 2) {
        unsigned p = packed[sorted_row[start + e]];
        float dv = __uint_as_float(p & 0xffff0000u);
        float2 m = M2[(p & 127u) * 32 + sub];
        ax += dv * m.x; ay += dv * m.y;
    }
    ax += __shfl_xor(ax, 32, 64);
    ay += __shfl_xor(ay, 32, 64);
    if (half == 0) {
        unsigned ps = packed[n];  // self-loop term
        float dvs = __uint_as_float(ps & 0xffff0000u);
        float2 ms = M2[(ps & 127u) * 32 + sub];
        ax += dvs * ms.x; ay += dvs * ms.y;
        float di = dinv[n];
        const float2* b2 = (const float2*)bias;
        float2 bb = b2[sub];
        float2* h2 = (float2*)h;
        h2[(size_t)n * 32 + sub] = make_float2(fmaxf(ax * di + bb.x, 0.0f),
                                               fmaxf(ay * di + bb.y, 0.0f));
    }
}

// t' = bf16( dinv[n] * (h @ W) )  (layers 1,2)
__global__ __launch_bounds__(256) void k_linear(const float* __restrict__ hin,
                                                const float* __restrict__ W,
                                                const float* __restrict__ dinv,
                                                unsigned short* __restrict__ t) {
    int lane = threadIdx.x & 63;
    int wid = (blockIdx.x * blockDim.x + threadIdx.x) >> 6;
    float wreg[H];
#pragma unroll
    for (int k = 0; k < H; ++k) wreg[k] = W[k * H + lane];
    int n0 = wid * LIN_NODES_PER_WAVE;
    if (n0 >= N_NODES) return;
    for (int i = 0; i < LIN_NODES_PER_WAVE; ++i) {
        int n = __builtin_amdgcn_readfirstlane(n0 + i);
        if (n >= N_NODES) break;
        const float* hr = hin + (size_t)n * H;
        float acc = 0.0f;
#pragma unroll
        for (int k = 0; k < H; ++k) acc += hr[k] * wreg[k];
        t[(size_t)n * H + lane] = f2bf(acc * dinv[n]);
    }
}

// layers 1-2 gather + finalize: one wave per node; 2 half-waves, bf16x2 channels
__global__ void k_gather(const int* __restrict__ sorted_row, const int* __restrict__ row_start,
                         const int* __restrict__ degi, const unsigned short* __restrict__ t,
                         const float* __restrict__ dinv, const float* __restrict__ bias,
                         float* __restrict__ h) {
    int gid = blockIdx.x * blockDim.x + threadIdx.x;
    int n = gid >> 6;
    if (n >= N_NODES) return;
    int lane = threadIdx.x & 63;
    int half = lane >> 5;
    int sub = lane & 31;
    const unsigned* t2 = (const unsigned*)t;
    int start = row_start[n];
    int d = degi[n];
    float ax = 0.0f, ay = 0.0f;
    int e = half;
    for (; e + 14 < d; e += 16) {
        unsigned p[8];
#pragma unroll
        for (int j = 0; j < 8; ++j)
            p[j] = t2[(size_t)sorted_row[start + e + 2 * j] * 32 + sub];
#pragma unroll
        for (int j = 0; j < 8; ++j) { ax += bflo(p[j]); ay += bfhi(p[j]); }
    }
    for (; e + 6 < d; e += 8) {
        unsigned p[4];
#pragma unroll
        for (int j = 0; j < 4; ++j)
            p[j] = t2[(size_t)sorted_row[start + e + 2 * j] * 32 + sub];
#pragma unroll
        for (int j = 0; j < 4; ++j) { ax += bflo(p[j]); ay += bfhi(p[j]); }
    }
    for (; e < d; e += 2) {
        unsigned p = t2[(size_t)sorted_row[start + e] * 32 + sub];
        ax += bflo(p); ay += bfhi(p);
    }
    ax += __shfl_xor(ax, 32, 64);
    ay += __shfl_xor(ay, 32, 64);
    if (half == 0) {
        unsigned self = t2[(size_t)n * 32 + sub];
        ax += bflo(self); ay += bfhi(self);
        float di = dinv[n];
        const float2* b2 = (const float2*)bias;
        float2 bb = b2[sub];
        float2* h2 = (float2*)h;
        float2 hp = h2[(size_t)n * 32 + sub];  // residual (layers 1,2 only)
        float vx = hp.x + fmaxf(ax * di + bb.x, 0.0f);
        float vy = hp.y + fmaxf(ay * di + bb.y, 0.0f);
        h2[(size_t)n * 32 + sub] = make_float2(vx, vy);
    }
}

// fused mean-pool + MLP: one wave per graph (batch sorted -> binary search)
__global__ void k_poolmlp(const float* __restrict__ h, const int* __restrict__ batch,
                          const float* __restrict__ w1, const float* __restrict__ b1,
                          const float* __restrict__ w2, const float* __restrict__ b2,
                          const float* __restrict__ w3, const float* __restrict__ b3,
                          float* __restrict__ out) {
    __shared__ float sg[H];
    __shared__ float s1[32];
    __shared__ float s2[16];
    int g = blockIdx.x, tid = threadIdx.x;
    int lo = 0, hi = N_NODES;
    while (lo < hi) { int mid = (lo + hi) >> 1; if (batch[mid] < g) lo = mid + 1; else hi = mid; }
    int lo2 = lo, hi2 = N_NODES;
    while (lo2 < hi2) { int mid = (lo2 + hi2) >> 1; if (batch[mid] < g + 1) lo2 = mid + 1; else hi2 = mid; }
    float acc = 0.0f;
    for (int n = lo; n < lo2; ++n) acc += h[(size_t)n * H + tid];
    float cntf = (float)(lo2 - lo);
    sg[tid] = acc / fmaxf(cntf, 1.0f);
    __syncthreads();
    if (tid < 32) {
        float a = b1[tid];
#pragma unroll
        for (int k = 0; k < H; ++k) a += sg[k] * w1[k * 32 + tid];
        s1[tid] = fmaxf(a, 0.0f);
    }
    __syncthreads();
    if (tid < 16) {
        float a = b2[tid];
#pragma unroll
        for (int k = 0; k < 32; ++k) a += s1[k] * w2[k * 16 + tid];
        s2[tid] = fmaxf(a, 0.0f);
    }
    __syncthreads();
    if (tid == 0) {
        float a = b3[0];
#pragma unroll
        for (int k = 0; k < 16; ++k) a += s2[k] * w3[k];
        out[g] = a;
    }
}

// ---------------- launch ----------------

extern "C" void kernel_launch(void* const* d_in, const int* in_sizes, int n_in,
                              void* d_out, int out_size, void* d_ws, size_t ws_size,
                              hipStream_t stream) {
    const int*   x      = (const int*)d_in[0];
    const int*   eidx   = (const int*)d_in[1];   // (2, E): row = eidx, col = eidx + E
    const int*   batch  = (const int*)d_in[2];
    const float* emb    = (const float*)d_in[3];
    const float* conv_w = (const float*)d_in[4];
    const float* conv_b = (const float*)d_in[5];
    const float* w1     = (const float*)d_in[6];
    const float* b1     = (const float*)d_in[7];
    const float* w2     = (const float*)d_in[8];
    const float* b2     = (const float*)d_in[9];
    const float* w3     = (const float*)d_in[10];
    const float* b3     = (const float*)d_in[11];
    float* out = (float*)d_out;

    const int* row = eidx;
    const int* col = eidx + N_EDGES;

    // workspace layout (4-byte units)
    char* wsb = (char*)d_ws;
    size_t off = 0;
    auto alloc = [&](size_t elems) { void* p = wsb + off; off += ((elems * 4 + 255) & ~(size_t)255); return p; };
    int*      bcnt       = (int*)alloc(NBUCK);
    int*      bbase      = (int*)alloc(NBUCK + 1);
    int*      bcur       = (int*)alloc(NBUCK);
    int*      blkhist    = (int*)alloc((size_t)PART_BLOCKS * NBUCK);
    int*      row_start  = (int*)alloc(N_NODES);
    int*      degi       = (int*)alloc(N_NODES);
    float*    dinv       = (float*)alloc(N_NODES);
    unsigned* packed     = (unsigned*)alloc(N_NODES);
    float*    M          = (float*)alloc(VOCAB * H);
    int*      sorted_row = (int*)alloc(N_EDGES);
    float*    h          = (float*)alloc((size_t)N_NODES * H);
    unsigned short* t    = (unsigned short*)alloc((size_t)N_NODES * H / 2);  // bf16

    // packed staging (int[N_EDGES] = 12.8 MB) aliases t (dead until k_linear layer 1)
    int* staging = (int*)t;

    const int B = 256;
    const int gNH = (N_NODES * H + B - 1) / B;
    const int gLin = ((N_NODES + LIN_NODES_PER_WAVE - 1) / LIN_NODES_PER_WAVE * 64 + B - 1) / B;

    hipLaunchKernelGGL(k_init, dim3((NBUCK + B - 1) / B), dim3(B), 0, stream, bcnt);
    hipLaunchKernelGGL(k_bhist, dim3(PART_BLOCKS), dim3(256), 0, stream, col, bcnt, blkhist);
    hipLaunchKernelGGL(k_bscan, dim3(1), dim3(1024), 0, stream, bcnt, bbase, bcur);
    hipLaunchKernelGGL(k_binA, dim3(PART_BLOCKS), dim3(1024), 0, stream,
                       row, col, blkhist, bcur, staging);
    hipLaunchKernelGGL(k_binB, dim3(NBUCK), dim3(256), 0, stream, staging, bbase, x,
                       sorted_row, degi, row_start, dinv, packed);

    // layer 0: vocabulary-factored
    hipLaunchKernelGGL(k_premix, dim3(VOCAB), dim3(H), 0, stream, emb, conv_w, M);
    hipLaunchKernelGGL(k_gather0, dim3(gNH), dim3(B), 0, stream,
                       sorted_row, row_start, degi, packed, M, dinv, conv_b, h);

    // layers 1,2
    for (int layer = 1; layer < N_LAYERS; ++layer) {
        hipLaunchKernelGGL(k_linear, dim3(gLin), dim3(B), 0, stream,
                           h, conv_w + (size_t)layer * H * H, dinv, t);
        hipLaunchKernelGGL(k_gather, dim3(gNH), dim3(B), 0, stream,
                           sorted_row, row_start, degi, t, dinv,
                           conv_b + (size_t)layer * H, h);
    }

    hipLaunchKernelGGL(k_poolmlp, dim3(N_GRAPHS), dim3(64), 0, stream,
                       h, batch, w1, b1, w2, b2, w3, b3, out);

    (void)in_sizes; (void)n_in; (void)out_size; (void)ws_size;
}